// Round 16
// baseline (242.896 us; speedup 1.0000x reference)
//
#include <hip/hip_runtime.h>

#define BATCH   1024
#define MAXLEN  200
#define KCAPS   8
#define INU     256
#define OUTU    256
#define NEGPAD  -65535.0f
#define HSTR    264   // padded LDS row stride (floats)

typedef _Float16 f16;
typedef _Float16 f16x8 __attribute__((ext_vector_type(8)));
typedef float    f32x4 __attribute__((ext_vector_type(4)));

// ---------------- prep: Bcur copy + packed-frag S and S^T (hi/lo f16) ------
__global__ void k_prep(const float* __restrict__ S, const float* __restrict__ Bm,
                       f16* __restrict__ Shi, f16* __restrict__ Slo,
                       f16* __restrict__ Thi, f16* __restrict__ Tlo,
                       float* __restrict__ Bcur) {
    int idx = blockIdx.x * 256 + threadIdx.x;    // 0 .. 65535
    if (idx < KCAPS * MAXLEN) Bcur[idx] = Bm[idx];
    int j    = idx & 7;
    int lane = (idx >> 3) & 63;
    int nf   = (idx >> 9) & 15;
    int ks   = idx >> 13;
    int k = ks * 32 + (lane >> 4) * 8 + j;
    int n = nf * 16 + (lane & 15);
    float vS = S[k * 256 + n];
    f16 hS = (f16)vS;
    Shi[idx] = hS;
    Slo[idx] = (f16)(vS - (float)hS);
    float vT = S[n * 256 + k];
    f16 hT = (f16)vT;
    Thi[idx] = hT;
    Tlo[idx] = (f16)(vT - (float)hT);
}

// phase-E fragment: delta rows MF*16+r15, all 8 ks, burst-loaded
#define EFRAG(MF, ACC) do {                                                          \
    const int l_  = (MF) * 16 + r15;                                                 \
    const int lc_ = (l_ < MAXLEN) ? l_ : (MAXLEN - 1);                               \
    const float* ap_ = lb + (size_t)lc_ * INU + q * 8;                               \
    f32x4 va[8], vb[8];                                                              \
    _Pragma("unroll")                                                                \
    for (int ks = 0; ks < 8; ks++) {                                                 \
        va[ks] = *reinterpret_cast<const f32x4*>(ap_ + ks * 32);                     \
        vb[ks] = *reinterpret_cast<const f32x4*>(ap_ + ks * 32 + 4);                 \
    }                                                                                \
    _Pragma("unroll")                                                                \
    for (int ks = 0; ks < 8; ks++) {                                                 \
        const int ob_ = ks * 32 + q * 8;                                             \
        f32x4 h0 = *reinterpret_cast<const f32x4*>(&GH[r15 * HSTR + ob_]);           \
        f32x4 h1 = *reinterpret_cast<const f32x4*>(&GH[r15 * HSTR + ob_ + 4]);       \
        f16x8 bh, bl, ah, al;                                                        \
        _Pragma("unroll")                                                            \
        for (int j = 0; j < 4; j++) { f16 t = (f16)h0[j]; bh[j] = t; bl[j] = (f16)(h0[j] - (float)t); } \
        _Pragma("unroll")                                                            \
        for (int j = 0; j < 4; j++) { f16 t = (f16)h1[j]; bh[4+j] = t; bl[4+j] = (f16)(h1[j] - (float)t); } \
        _Pragma("unroll")                                                            \
        for (int j = 0; j < 4; j++) { f16 t = (f16)va[ks][j]; ah[j] = t; al[j] = (f16)(va[ks][j] - (float)t); } \
        _Pragma("unroll")                                                            \
        for (int j = 0; j < 4; j++) { f16 t = (f16)vb[ks][j]; ah[4+j] = t; al[4+j] = (f16)(vb[ks][j] - (float)t); } \
        ACC = __builtin_amdgcn_mfma_f32_16x16x32_f16(ah, bh, ACC, 0, 0, 0);          \
        ACC = __builtin_amdgcn_mfma_f32_16x16x32_f16(al, bh, ACC, 0, 0, 0);          \
        ACC = __builtin_amdgcn_mfma_f32_16x16x32_f16(ah, bl, ACC, 0, 0, 0);          \
    }                                                                                \
} while (0)

// ---------------- fused per-iteration kernel --------------------------------
// A: softmax (wave per k; masked rows get W = 0 exactly via exp underflow).
// B: G = W @ low over ALL 200 rows (static trip count, burst-8 f32x4 loads,
//    one row-stream per wave), 8 partials serialized-reduced into GH's two
//    16-row banks.  C: MFMA absorbs the bank sum (shfl_xor 32), squash.
// D: T = H @ S^T (MFMA).  E: delta = low @ T^T (MFMA, burst loads, b-major).
__global__ __launch_bounds__(512, 4) void k_G(const float* __restrict__ Bcur,
                                              const int*   __restrict__ seq_len,
                                              const float* __restrict__ low,
                                              const f16*   __restrict__ Shi,
                                              const f16*   __restrict__ Slo,
                                              const f16*   __restrict__ Thi,
                                              const f16*   __restrict__ Tlo,
                                              float*       __restrict__ partials,
                                              float*       __restrict__ out,
                                              int do_T) {
    __shared__ float Wl[KCAPS * MAXLEN];     // 6.4 KB
    __shared__ float GH[16 * HSTR];          // 16.9 KB: Gbanks -> Hl -> Tl
    const int b   = blockIdx.x;
    const int tid = threadIdx.x;
    const int len = seq_len[b];

    for (int i = tid; i < KCAPS * MAXLEN; i += 512) Wl[i] = Bcur[i];
    __syncthreads();

    // phase A: masked softmax, one 64-lane wave per k
    {
        const int k  = tid >> 6;
        const int ln = tid & 63;
        float m = -3.4e38f;
        for (int l = ln; l < MAXLEN; l += 64) {
            float v = (l < len) ? Wl[k * MAXLEN + l] : NEGPAD;
            m = fmaxf(m, v);
        }
        #pragma unroll
        for (int off = 32; off >= 1; off >>= 1) m = fmaxf(m, __shfl_xor(m, off));
        float ssum = 0.f;
        for (int l = ln; l < MAXLEN; l += 64) {
            float v = (l < len) ? Wl[k * MAXLEN + l] : NEGPAD;
            ssum += __expf(v - m);
        }
        #pragma unroll
        for (int off = 32; off >= 1; off >>= 1) ssum += __shfl_xor(ssum, off);
        float inv = 1.f / ssum;
        for (int l = ln; l < MAXLEN; l += 64) {
            float v = (l < len) ? Wl[k * MAXLEN + l] : NEGPAD;
            Wl[k * MAXLEN + l] = __expf(v - m) * inv;   // exactly 0 for l>=len (len>0)
        }
    }
    __syncthreads();

    const float* lb = low + (size_t)b * (MAXLEN * INU);
    const int wv = tid >> 6, lane = tid & 63;
    const int r15 = lane & 15, q = lane >> 4;

    // phase B: G[k,:] = sum_l W[k,l]*low[l,:], ALL 200 rows, static counts.
    // Wave wv streams rows l = wv + 8j (j=0..24): 3 bursts of 8 + 1 tail.
    {
        const float* cb = lb + lane * 4;
        f32x4 g[KCAPS];
        #pragma unroll
        for (int k = 0; k < KCAPS; k++) g[k] = (f32x4){0.f, 0.f, 0.f, 0.f};
        #pragma unroll
        for (int jb = 0; jb < 3; jb++) {
            f32x4 v[8];
            #pragma unroll
            for (int u = 0; u < 8; u++)
                v[u] = *reinterpret_cast<const f32x4*>(cb + (size_t)(wv + (jb * 8 + u) * 8) * INU);
            #pragma unroll
            for (int u = 0; u < 8; u++) {
                const int l = wv + (jb * 8 + u) * 8;
                #pragma unroll
                for (int k = 0; k < KCAPS; k++) {
                    const float w = Wl[k * MAXLEN + l];   // wave-uniform broadcast
                    g[k][0] = fmaf(w, v[u][0], g[k][0]);
                    g[k][1] = fmaf(w, v[u][1], g[k][1]);
                    g[k][2] = fmaf(w, v[u][2], g[k][2]);
                    g[k][3] = fmaf(w, v[u][3], g[k][3]);
                }
            }
        }
        {   // tail row j = 24: l = wv + 192
            const int l = wv + 192;
            f32x4 v = *reinterpret_cast<const f32x4*>(cb + (size_t)l * INU);
            #pragma unroll
            for (int k = 0; k < KCAPS; k++) {
                const float w = Wl[k * MAXLEN + l];
                g[k][0] = fmaf(w, v[0], g[k][0]);
                g[k][1] = fmaf(w, v[1], g[k][1]);
                g[k][2] = fmaf(w, v[2], g[k][2]);
                g[k][3] = fmaf(w, v[3], g[k][3]);
            }
        }
        // serialized reduce: even waves -> bank0 (rows 0-7), odd -> bank1 (8-15)
        const int bank = wv & 1;
        const int step = wv >> 1;
        #pragma unroll
        for (int s = 0; s < 4; s++) {
            if (step == s) {
                if (s == 0) {
                    #pragma unroll
                    for (int k = 0; k < KCAPS; k++)
                        *reinterpret_cast<f32x4*>(&GH[(bank * 8 + k) * HSTR + lane * 4]) = g[k];
                } else {
                    #pragma unroll
                    for (int k = 0; k < KCAPS; k++) {
                        float* p = &GH[(bank * 8 + k) * HSTR + lane * 4];
                        f32x4 t = *reinterpret_cast<const f32x4*>(p);
                        *reinterpret_cast<f32x4*>(p) = t + g[k];
                    }
                }
            }
            __syncthreads();
        }
    }

    // phase C (MFMA): D = Gbanks(16 rows) @ S; hp[k] = D[k] + D[k+8] via
    // shfl_xor(32). Wave wv covers nf = 2wv, 2wv+1.
    f32x4 aC[2];
    aC[0] = (f32x4){0.f, 0.f, 0.f, 0.f};
    aC[1] = (f32x4){0.f, 0.f, 0.f, 0.f};
    #pragma unroll
    for (int ks = 0; ks < 8; ks++) {
        const float* gp = &GH[r15 * HSTR + ks * 32 + q * 8];
        f32x4 a0 = *reinterpret_cast<const f32x4*>(gp);
        f32x4 a1 = *reinterpret_cast<const f32x4*>(gp + 4);
        f16x8 ah, al;
        #pragma unroll
        for (int j = 0; j < 4; j++) {
            f16 t = (f16)a0[j]; ah[j] = t; al[j] = (f16)(a0[j] - (float)t);
        }
        #pragma unroll
        for (int j = 0; j < 4; j++) {
            f16 t = (f16)a1[j]; ah[4 + j] = t; al[4 + j] = (f16)(a1[j] - (float)t);
        }
        #pragma unroll
        for (int i = 0; i < 2; i++) {
            const int nf = wv * 2 + i;
            f16x8 bh = *reinterpret_cast<const f16x8*>(Shi + (ks * 16 + nf) * 512 + lane * 8);
            f16x8 bl = *reinterpret_cast<const f16x8*>(Slo + (ks * 16 + nf) * 512 + lane * 8);
            aC[i] = __builtin_amdgcn_mfma_f32_16x16x32_f16(ah, bh, aC[i], 0, 0, 0);
            aC[i] = __builtin_amdgcn_mfma_f32_16x16x32_f16(al, bh, aC[i], 0, 0, 0);
            aC[i] = __builtin_amdgcn_mfma_f32_16x16x32_f16(ah, bl, aC[i], 0, 0, 0);
        }
    }
    // bank-sum + squash: thread holds hp[k=q*4+r][o=(2wv+i)*16+r15], k<8 at q<2
    float s0, s1;
    {
        #pragma unroll
        for (int i = 0; i < 2; i++)
            #pragma unroll
            for (int r = 0; r < 4; r++) aC[i][r] += __shfl_xor(aC[i][r], 32);
        float n0 = aC[0][0]*aC[0][0] + aC[0][1]*aC[0][1] + aC[0][2]*aC[0][2] + aC[0][3]*aC[0][3];
        float n1 = aC[1][0]*aC[1][0] + aC[1][1]*aC[1][1] + aC[1][2]*aC[1][2] + aC[1][3]*aC[1][3];
        n0 += __shfl_xor(n0, 16);
        n1 += __shfl_xor(n1, 16);
        s0 = n0 / (1.f + n0) * (1.f / sqrtf(n0 + 1e-9f));
        s1 = n1 / (1.f + n1) * (1.f / sqrtf(n1 + 1e-9f));
    }
    if (!do_T) {
        if (q < 2) {
            #pragma unroll
            for (int r = 0; r < 4; r++) {
                out[((size_t)b * KCAPS + q * 4 + r) * OUTU + (wv * 2 + 0) * 16 + r15] = s0 * aC[0][r];
                out[((size_t)b * KCAPS + q * 4 + r) * OUTU + (wv * 2 + 1) * 16 + r15] = s1 * aC[1][r];
            }
        }
        return;
    }
    __syncthreads();                       // all phase-C reads of GH done
    // GH becomes Hl: rows 0-7 = H, rows 8-15 = 0 (every lane writes its cell)
    #pragma unroll
    for (int r = 0; r < 4; r++) {
        GH[(q * 4 + r) * HSTR + (wv * 2 + 0) * 16 + r15] = (q < 2) ? s0 * aC[0][r] : 0.f;
        GH[(q * 4 + r) * HSTR + (wv * 2 + 1) * 16 + r15] = (q < 2) ? s1 * aC[1][r] : 0.f;
    }
    __syncthreads();

    // phase D (MFMA): T[k][e] = sum_o H[k][o]*S[e][o]
    f32x4 aD[2];
    aD[0] = (f32x4){0.f, 0.f, 0.f, 0.f};
    aD[1] = (f32x4){0.f, 0.f, 0.f, 0.f};
    #pragma unroll
    for (int ks = 0; ks < 8; ks++) {
        const float* hp = &GH[r15 * HSTR + ks * 32 + q * 8];
        f32x4 a0 = *reinterpret_cast<const f32x4*>(hp);
        f32x4 a1 = *reinterpret_cast<const f32x4*>(hp + 4);
        f16x8 ah, al;
        #pragma unroll
        for (int j = 0; j < 4; j++) {
            f16 t = (f16)a0[j]; ah[j] = t; al[j] = (f16)(a0[j] - (float)t);
        }
        #pragma unroll
        for (int j = 0; j < 4; j++) {
            f16 t = (f16)a1[j]; ah[4 + j] = t; al[4 + j] = (f16)(a1[j] - (float)t);
        }
        #pragma unroll
        for (int i = 0; i < 2; i++) {
            const int nf = wv * 2 + i;
            f16x8 bh = *reinterpret_cast<const f16x8*>(Thi + (ks * 16 + nf) * 512 + lane * 8);
            f16x8 bl = *reinterpret_cast<const f16x8*>(Tlo + (ks * 16 + nf) * 512 + lane * 8);
            aD[i] = __builtin_amdgcn_mfma_f32_16x16x32_f16(ah, bh, aD[i], 0, 0, 0);
            aD[i] = __builtin_amdgcn_mfma_f32_16x16x32_f16(al, bh, aD[i], 0, 0, 0);
            aD[i] = __builtin_amdgcn_mfma_f32_16x16x32_f16(ah, bl, aD[i], 0, 0, 0);
        }
    }
    __syncthreads();                       // all phase-D reads of GH done
    // GH becomes Tl: rows 0-7 = T, rows 8-15 = 0
    #pragma unroll
    for (int r = 0; r < 4; r++) {
        GH[(q * 4 + r) * HSTR + (wv * 2 + 0) * 16 + r15] = (q < 2) ? aD[0][r] : 0.f;
        GH[(q * 4 + r) * HSTR + (wv * 2 + 1) * 16 + r15] = (q < 2) ? aD[1][r] : 0.f;
    }
    __syncthreads();

    // phase E (MFMA): delta_T[l][k] = sum_e low[l,e]*T[k,e]; b-major partials
    f32x4 accA = (f32x4){0.f, 0.f, 0.f, 0.f};
    f32x4 accB = (f32x4){0.f, 0.f, 0.f, 0.f};
    EFRAG(wv, accA);
    if (wv < 5) EFRAG(wv + 8, accB);

    if (r15 < KCAPS) {
        const int kcol = r15;
        float* pb = partials + (size_t)b * (KCAPS * MAXLEN);
        {   // frag A rows: l = wv*16 + q*4 + r  (max 127 < 200, no guard)
            const int lbase = wv * 16 + q * 4;
            #pragma unroll
            for (int r = 0; r < 4; r++)
                pb[(lbase + r) * KCAPS + kcol] = accA[r];
        }
        if (wv < 5) {   // frag B rows: l = (wv+8)*16 + q*4 + r (may exceed 199)
            const int lbase = (wv + 8) * 16 + q * 4;
            #pragma unroll
            for (int r = 0; r < 4; r++) {
                const int l = lbase + r;
                if (l < MAXLEN)
                    pb[l * KCAPS + kcol] = accB[r];
            }
        }
    }
}

// ---------------- B update: Bcur[k*200+l] += sum_b partials[b][l*8+k] ------
__global__ __launch_bounds__(256) void k_update(const float* __restrict__ partials,
                                                float* __restrict__ Bcur) {
    __shared__ float red[256];
    const int j   = blockIdx.x;            // 0..1599 ; l = j>>3, k = j&7
    const int tid = threadIdx.x;
    float s = 0.f;
    #pragma unroll
    for (int jj = 0; jj < BATCH / 256; jj++)
        s += partials[(size_t)(tid + jj * 256) * (KCAPS * MAXLEN) + j];
    red[tid] = s;
    __syncthreads();
    for (int st = 128; st > 0; st >>= 1) {
        if (tid < st) red[tid] += red[tid + st];
        __syncthreads();
    }
    if (tid == 0) Bcur[(j & 7) * MAXLEN + (j >> 3)] += red[0];
}

extern "C" void kernel_launch(void* const* d_in, const int* in_sizes, int n_in,
                              void* d_out, int out_size, void* d_ws, size_t ws_size,
                              hipStream_t stream) {
    const float* low = (const float*)d_in[0];
    const float* S   = (const float*)d_in[1];
    const float* Bm  = (const float*)d_in[2];
    const int*   seq = (const int*)d_in[3];
    float* out = (float*)d_out;

    char* ws = (char*)d_ws;
    float* Bcur     = (float*)ws;                     // 6,400 B
    float* partials = (float*)(ws + 6400);            // 6,553,600 B
    f16*   Shi      = (f16*)(ws + 6560000);           // 131,072 B
    f16*   Slo      = (f16*)(ws + 6691072);           // 131,072 B
    f16*   Thi      = (f16*)(ws + 6822144);           // 131,072 B
    f16*   Tlo      = (f16*)(ws + 6953216);           // 131,072 B

    k_prep<<<256, 256, 0, stream>>>(S, Bm, Shi, Slo, Thi, Tlo, Bcur);
    for (int it = 0; it < 3; it++) {
        int last = (it == 2);
        k_G<<<BATCH, 512, 0, stream>>>(Bcur, seq, low, Shi, Slo, Thi, Tlo,
                                       partials, out, last ? 0 : 1);
        if (!last) k_update<<<KCAPS * MAXLEN, 256, 0, stream>>>(partials, Bcur);
    }
}

// Round 17
// 200.660 us; speedup vs baseline: 1.2105x; 1.2105x over previous
//
#include <hip/hip_runtime.h>

#define BATCH   1024
#define MAXLEN  200
#define KCAPS   8
#define INU     256
#define OUTU    256
#define NEGPAD  -65535.0f
#define HSTR    264   // padded LDS row stride (floats)

typedef _Float16 f16;
typedef _Float16 f16x8 __attribute__((ext_vector_type(8)));
typedef float    f32x4 __attribute__((ext_vector_type(4)));

// ---------------- prep: Bcur copy + packed-frag S and S^T (hi/lo f16) ------
__global__ void k_prep(const float* __restrict__ S, const float* __restrict__ Bm,
                       f16* __restrict__ Shi, f16* __restrict__ Slo,
                       f16* __restrict__ Thi, f16* __restrict__ Tlo,
                       float* __restrict__ Bcur) {
    int idx = blockIdx.x * 256 + threadIdx.x;    // 0 .. 65535
    if (idx < KCAPS * MAXLEN) Bcur[idx] = Bm[idx];
    int j    = idx & 7;
    int lane = (idx >> 3) & 63;
    int nf   = (idx >> 9) & 15;
    int ks   = idx >> 13;
    int k = ks * 32 + (lane >> 4) * 8 + j;
    int n = nf * 16 + (lane & 15);
    float vS = S[k * 256 + n];
    f16 hS = (f16)vS;
    Shi[idx] = hS;
    Slo[idx] = (f16)(vS - (float)hS);
    float vT = S[n * 256 + k];
    f16 hT = (f16)vT;
    Thi[idx] = hT;
    Tlo[idx] = (f16)(vT - (float)hT);
}

// phase-E fragment: delta rows MF*16+r15, all 8 ks, burst-loaded
#define EFRAG(MF, ACC) do {                                                          \
    const int l_  = (MF) * 16 + r15;                                                 \
    const int lc_ = (l_ < MAXLEN) ? l_ : (MAXLEN - 1);                               \
    const float* ap_ = lb + (size_t)lc_ * INU + q * 8;                               \
    f32x4 va[8], vb[8];                                                              \
    _Pragma("unroll")                                                                \
    for (int ks = 0; ks < 8; ks++) {                                                 \
        va[ks] = *reinterpret_cast<const f32x4*>(ap_ + ks * 32);                     \
        vb[ks] = *reinterpret_cast<const f32x4*>(ap_ + ks * 32 + 4);                 \
    }                                                                                \
    _Pragma("unroll")                                                                \
    for (int ks = 0; ks < 8; ks++) {                                                 \
        const int ob_ = ks * 32 + q * 8;                                             \
        f32x4 h0 = *reinterpret_cast<const f32x4*>(&GH[r15 * HSTR + ob_]);           \
        f32x4 h1 = *reinterpret_cast<const f32x4*>(&GH[r15 * HSTR + ob_ + 4]);       \
        f16x8 bh, bl, ah, al;                                                        \
        _Pragma("unroll")                                                            \
        for (int j = 0; j < 4; j++) { f16 t = (f16)h0[j]; bh[j] = t; bl[j] = (f16)(h0[j] - (float)t); } \
        _Pragma("unroll")                                                            \
        for (int j = 0; j < 4; j++) { f16 t = (f16)h1[j]; bh[4+j] = t; bl[4+j] = (f16)(h1[j] - (float)t); } \
        _Pragma("unroll")                                                            \
        for (int j = 0; j < 4; j++) { f16 t = (f16)va[ks][j]; ah[j] = t; al[j] = (f16)(va[ks][j] - (float)t); } \
        _Pragma("unroll")                                                            \
        for (int j = 0; j < 4; j++) { f16 t = (f16)vb[ks][j]; ah[4+j] = t; al[4+j] = (f16)(vb[ks][j] - (float)t); } \
        ACC = __builtin_amdgcn_mfma_f32_16x16x32_f16(ah, bh, ACC, 0, 0, 0);          \
        ACC = __builtin_amdgcn_mfma_f32_16x16x32_f16(al, bh, ACC, 0, 0, 0);          \
        ACC = __builtin_amdgcn_mfma_f32_16x16x32_f16(ah, bl, ACC, 0, 0, 0);          \
    }                                                                                \
} while (0)

// ---------------- fused per-iteration kernel --------------------------------
// A: softmax (wave per k; masked rows have W = 0 exactly via exp underflow).
// B: G = W @ low, MASKED row range, 4-row chunks per wave with explicit
//    distance-1 prefetch (8 x f32x4 in flight/lane); 8 wave-partials reduce
//    into GH's two 16-row banks.  C: MFMA absorbs bank sum (shfl_xor 32),
//    squash.  D: T = H @ S^T (MFMA).  E: delta = low @ T^T (MFMA, b-major).
__global__ __launch_bounds__(512, 4) void k_G(const float* __restrict__ Bcur,
                                              const int*   __restrict__ seq_len,
                                              const float* __restrict__ low,
                                              const f16*   __restrict__ Shi,
                                              const f16*   __restrict__ Slo,
                                              const f16*   __restrict__ Thi,
                                              const f16*   __restrict__ Tlo,
                                              float*       __restrict__ partials,
                                              float*       __restrict__ out,
                                              int do_T) {
    __shared__ float Wl[KCAPS * MAXLEN];     // 6.4 KB
    __shared__ float GH[16 * HSTR];          // 16.9 KB: Gbanks -> Hl -> Tl
    const int b   = blockIdx.x;
    const int tid = threadIdx.x;
    const int len = seq_len[b];

    for (int i = tid; i < KCAPS * MAXLEN; i += 512) Wl[i] = Bcur[i];
    __syncthreads();

    // phase A: masked softmax, one 64-lane wave per k
    {
        const int k  = tid >> 6;
        const int ln = tid & 63;
        float m = -3.4e38f;
        for (int l = ln; l < MAXLEN; l += 64) {
            float v = (l < len) ? Wl[k * MAXLEN + l] : NEGPAD;
            m = fmaxf(m, v);
        }
        #pragma unroll
        for (int off = 32; off >= 1; off >>= 1) m = fmaxf(m, __shfl_xor(m, off));
        float ssum = 0.f;
        for (int l = ln; l < MAXLEN; l += 64) {
            float v = (l < len) ? Wl[k * MAXLEN + l] : NEGPAD;
            ssum += __expf(v - m);
        }
        #pragma unroll
        for (int off = 32; off >= 1; off >>= 1) ssum += __shfl_xor(ssum, off);
        float inv = 1.f / ssum;
        for (int l = ln; l < MAXLEN; l += 64) {
            float v = (l < len) ? Wl[k * MAXLEN + l] : NEGPAD;
            Wl[k * MAXLEN + l] = __expf(v - m) * inv;   // exactly 0 for l>=len (len>0)
        }
    }
    __syncthreads();

    const float* lb = low + (size_t)b * (MAXLEN * INU);
    const int wv = tid >> 6, lane = tid & 63;
    const int r15 = lane & 15, q = lane >> 4;

    // phase B: masked, 4-row chunks per wave (stride 8 chunks), f32x4 full-row
    // loads, explicit distance-1 prefetch. Tail rows (l in [lim, 4*nb)) have
    // W == 0 exactly and l <= 199, so they contribute nothing and stay in-bounds.
    {
        const int lim = (len == 0) ? MAXLEN : len;
        const int nb  = (lim + 3) >> 2;              // # 4-row chunks
        const float* cb = lb + lane * 4;
        f32x4 g[KCAPS];
        #pragma unroll
        for (int k = 0; k < KCAPS; k++) g[k] = (f32x4){0.f, 0.f, 0.f, 0.f};
        int c = wv;
        if (c < nb) {
            f32x4 c0 = *reinterpret_cast<const f32x4*>(cb + (size_t)(4 * c + 0) * INU);
            f32x4 c1 = *reinterpret_cast<const f32x4*>(cb + (size_t)(4 * c + 1) * INU);
            f32x4 c2 = *reinterpret_cast<const f32x4*>(cb + (size_t)(4 * c + 2) * INU);
            f32x4 c3 = *reinterpret_cast<const f32x4*>(cb + (size_t)(4 * c + 3) * INU);
            for (;;) {
                const int cn = c + 8;
                const bool more = (cn < nb);         // wave-uniform
                f32x4 n0, n1, n2, n3;
                if (more) {
                    n0 = *reinterpret_cast<const f32x4*>(cb + (size_t)(4 * cn + 0) * INU);
                    n1 = *reinterpret_cast<const f32x4*>(cb + (size_t)(4 * cn + 1) * INU);
                    n2 = *reinterpret_cast<const f32x4*>(cb + (size_t)(4 * cn + 2) * INU);
                    n3 = *reinterpret_cast<const f32x4*>(cb + (size_t)(4 * cn + 3) * INU);
                }
                const int l0 = 4 * c;
                #pragma unroll
                for (int k = 0; k < KCAPS; k++) {
                    const float w0 = Wl[k * MAXLEN + l0];       // wave-uniform broadcast
                    const float w1 = Wl[k * MAXLEN + l0 + 1];
                    const float w2 = Wl[k * MAXLEN + l0 + 2];
                    const float w3 = Wl[k * MAXLEN + l0 + 3];
                    #pragma unroll
                    for (int j = 0; j < 4; j++) {
                        g[k][j] = fmaf(w0, c0[j], g[k][j]);
                        g[k][j] = fmaf(w1, c1[j], g[k][j]);
                        g[k][j] = fmaf(w2, c2[j], g[k][j]);
                        g[k][j] = fmaf(w3, c3[j], g[k][j]);
                    }
                }
                if (!more) break;
                c = cn; c0 = n0; c1 = n1; c2 = n2; c3 = n3;
            }
        }
        // reduce 8 wave-partials: even waves -> bank0 (rows 0-7), odd -> bank1
        const int bank = wv & 1;
        const int step = wv >> 1;
        #pragma unroll
        for (int s = 0; s < 4; s++) {
            if (step == s) {
                if (s == 0) {
                    #pragma unroll
                    for (int k = 0; k < KCAPS; k++)
                        *reinterpret_cast<f32x4*>(&GH[(bank * 8 + k) * HSTR + lane * 4]) = g[k];
                } else {
                    #pragma unroll
                    for (int k = 0; k < KCAPS; k++) {
                        float* p = &GH[(bank * 8 + k) * HSTR + lane * 4];
                        f32x4 t = *reinterpret_cast<const f32x4*>(p);
                        *reinterpret_cast<f32x4*>(p) = t + g[k];
                    }
                }
            }
            __syncthreads();
        }
    }

    // phase C (MFMA): D = Gbanks(16 rows) @ S; hp[k] = D[k] + D[k+8] via
    // shfl_xor(32). Wave wv covers nf = 2wv, 2wv+1.
    f32x4 aC[2];
    aC[0] = (f32x4){0.f, 0.f, 0.f, 0.f};
    aC[1] = (f32x4){0.f, 0.f, 0.f, 0.f};
    #pragma unroll
    for (int ks = 0; ks < 8; ks++) {
        const float* gp = &GH[r15 * HSTR + ks * 32 + q * 8];
        f32x4 a0 = *reinterpret_cast<const f32x4*>(gp);
        f32x4 a1 = *reinterpret_cast<const f32x4*>(gp + 4);
        f16x8 ah, al;
        #pragma unroll
        for (int j = 0; j < 4; j++) {
            f16 t = (f16)a0[j]; ah[j] = t; al[j] = (f16)(a0[j] - (float)t);
        }
        #pragma unroll
        for (int j = 0; j < 4; j++) {
            f16 t = (f16)a1[j]; ah[4 + j] = t; al[4 + j] = (f16)(a1[j] - (float)t);
        }
        #pragma unroll
        for (int i = 0; i < 2; i++) {
            const int nf = wv * 2 + i;
            f16x8 bh = *reinterpret_cast<const f16x8*>(Shi + (ks * 16 + nf) * 512 + lane * 8);
            f16x8 bl = *reinterpret_cast<const f16x8*>(Slo + (ks * 16 + nf) * 512 + lane * 8);
            aC[i] = __builtin_amdgcn_mfma_f32_16x16x32_f16(ah, bh, aC[i], 0, 0, 0);
            aC[i] = __builtin_amdgcn_mfma_f32_16x16x32_f16(al, bh, aC[i], 0, 0, 0);
            aC[i] = __builtin_amdgcn_mfma_f32_16x16x32_f16(ah, bl, aC[i], 0, 0, 0);
        }
    }
    // bank-sum + squash: thread holds hp[k=q*4+r][o=(2wv+i)*16+r15], k<8 at q<2
    float s0, s1;
    {
        #pragma unroll
        for (int i = 0; i < 2; i++)
            #pragma unroll
            for (int r = 0; r < 4; r++) aC[i][r] += __shfl_xor(aC[i][r], 32);
        float n0 = aC[0][0]*aC[0][0] + aC[0][1]*aC[0][1] + aC[0][2]*aC[0][2] + aC[0][3]*aC[0][3];
        float n1 = aC[1][0]*aC[1][0] + aC[1][1]*aC[1][1] + aC[1][2]*aC[1][2] + aC[1][3]*aC[1][3];
        n0 += __shfl_xor(n0, 16);
        n1 += __shfl_xor(n1, 16);
        s0 = n0 / (1.f + n0) * (1.f / sqrtf(n0 + 1e-9f));
        s1 = n1 / (1.f + n1) * (1.f / sqrtf(n1 + 1e-9f));
    }
    if (!do_T) {
        if (q < 2) {
            #pragma unroll
            for (int r = 0; r < 4; r++) {
                out[((size_t)b * KCAPS + q * 4 + r) * OUTU + (wv * 2 + 0) * 16 + r15] = s0 * aC[0][r];
                out[((size_t)b * KCAPS + q * 4 + r) * OUTU + (wv * 2 + 1) * 16 + r15] = s1 * aC[1][r];
            }
        }
        return;
    }
    __syncthreads();                       // all phase-C reads of GH done
    // GH becomes Hl: rows 0-7 = H, rows 8-15 = 0 (every lane writes its cell)
    #pragma unroll
    for (int r = 0; r < 4; r++) {
        GH[(q * 4 + r) * HSTR + (wv * 2 + 0) * 16 + r15] = (q < 2) ? s0 * aC[0][r] : 0.f;
        GH[(q * 4 + r) * HSTR + (wv * 2 + 1) * 16 + r15] = (q < 2) ? s1 * aC[1][r] : 0.f;
    }
    __syncthreads();

    // phase D (MFMA): T[k][e] = sum_o H[k][o]*S[e][o]
    f32x4 aD[2];
    aD[0] = (f32x4){0.f, 0.f, 0.f, 0.f};
    aD[1] = (f32x4){0.f, 0.f, 0.f, 0.f};
    #pragma unroll
    for (int ks = 0; ks < 8; ks++) {
        const float* hp = &GH[r15 * HSTR + ks * 32 + q * 8];
        f32x4 a0 = *reinterpret_cast<const f32x4*>(hp);
        f32x4 a1 = *reinterpret_cast<const f32x4*>(hp + 4);
        f16x8 ah, al;
        #pragma unroll
        for (int j = 0; j < 4; j++) {
            f16 t = (f16)a0[j]; ah[j] = t; al[j] = (f16)(a0[j] - (float)t);
        }
        #pragma unroll
        for (int j = 0; j < 4; j++) {
            f16 t = (f16)a1[j]; ah[4 + j] = t; al[4 + j] = (f16)(a1[j] - (float)t);
        }
        #pragma unroll
        for (int i = 0; i < 2; i++) {
            const int nf = wv * 2 + i;
            f16x8 bh = *reinterpret_cast<const f16x8*>(Thi + (ks * 16 + nf) * 512 + lane * 8);
            f16x8 bl = *reinterpret_cast<const f16x8*>(Tlo + (ks * 16 + nf) * 512 + lane * 8);
            aD[i] = __builtin_amdgcn_mfma_f32_16x16x32_f16(ah, bh, aD[i], 0, 0, 0);
            aD[i] = __builtin_amdgcn_mfma_f32_16x16x32_f16(al, bh, aD[i], 0, 0, 0);
            aD[i] = __builtin_amdgcn_mfma_f32_16x16x32_f16(ah, bl, aD[i], 0, 0, 0);
        }
    }
    __syncthreads();                       // all phase-D reads of GH done
    // GH becomes Tl: rows 0-7 = T, rows 8-15 = 0
    #pragma unroll
    for (int r = 0; r < 4; r++) {
        GH[(q * 4 + r) * HSTR + (wv * 2 + 0) * 16 + r15] = (q < 2) ? aD[0][r] : 0.f;
        GH[(q * 4 + r) * HSTR + (wv * 2 + 1) * 16 + r15] = (q < 2) ? aD[1][r] : 0.f;
    }
    __syncthreads();

    // phase E (MFMA): delta_T[l][k] = sum_e low[l,e]*T[k,e]; b-major partials
    f32x4 accA = (f32x4){0.f, 0.f, 0.f, 0.f};
    f32x4 accB = (f32x4){0.f, 0.f, 0.f, 0.f};
    EFRAG(wv, accA);
    if (wv < 5) EFRAG(wv + 8, accB);

    if (r15 < KCAPS) {
        const int kcol = r15;
        float* pb = partials + (size_t)b * (KCAPS * MAXLEN);
        {   // frag A rows: l = wv*16 + q*4 + r  (max 127 < 200, no guard)
            const int lbase = wv * 16 + q * 4;
            #pragma unroll
            for (int r = 0; r < 4; r++)
                pb[(lbase + r) * KCAPS + kcol] = accA[r];
        }
        if (wv < 5) {   // frag B rows: l = (wv+8)*16 + q*4 + r (may exceed 199)
            const int lbase = (wv + 8) * 16 + q * 4;
            #pragma unroll
            for (int r = 0; r < 4; r++) {
                const int l = lbase + r;
                if (l < MAXLEN)
                    pb[l * KCAPS + kcol] = accB[r];
            }
        }
    }
}

// ---------------- B update: Bcur[k*200+l] += sum_b partials[b][l*8+k] ------
__global__ __launch_bounds__(256) void k_update(const float* __restrict__ partials,
                                                float* __restrict__ Bcur) {
    __shared__ float red[256];
    const int j   = blockIdx.x;            // 0..1599 ; l = j>>3, k = j&7
    const int tid = threadIdx.x;
    float s = 0.f;
    #pragma unroll
    for (int jj = 0; jj < BATCH / 256; jj++)
        s += partials[(size_t)(tid + jj * 256) * (KCAPS * MAXLEN) + j];
    red[tid] = s;
    __syncthreads();
    for (int st = 128; st > 0; st >>= 1) {
        if (tid < st) red[tid] += red[tid + st];
        __syncthreads();
    }
    if (tid == 0) Bcur[(j & 7) * MAXLEN + (j >> 3)] += red[0];
}

extern "C" void kernel_launch(void* const* d_in, const int* in_sizes, int n_in,
                              void* d_out, int out_size, void* d_ws, size_t ws_size,
                              hipStream_t stream) {
    const float* low = (const float*)d_in[0];
    const float* S   = (const float*)d_in[1];
    const float* Bm  = (const float*)d_in[2];
    const int*   seq = (const int*)d_in[3];
    float* out = (float*)d_out;

    char* ws = (char*)d_ws;
    float* Bcur     = (float*)ws;                     // 6,400 B
    float* partials = (float*)(ws + 6400);            // 6,553,600 B
    f16*   Shi      = (f16*)(ws + 6560000);           // 131,072 B
    f16*   Slo      = (f16*)(ws + 6691072);           // 131,072 B
    f16*   Thi      = (f16*)(ws + 6822144);           // 131,072 B
    f16*   Tlo      = (f16*)(ws + 6953216);           // 131,072 B

    k_prep<<<256, 256, 0, stream>>>(S, Bm, Shi, Slo, Thi, Tlo, Bcur);
    for (int it = 0; it < 3; it++) {
        int last = (it == 2);
        k_G<<<BATCH, 512, 0, stream>>>(Bcur, seq, low, Shi, Slo, Thi, Tlo,
                                       partials, out, last ? 0 : 1);
        if (!last) k_update<<<KCAPS * MAXLEN, 256, 0, stream>>>(partials, Bcur);
    }
}

// Round 18
// 195.459 us; speedup vs baseline: 1.2427x; 1.0266x over previous
//
#include <hip/hip_runtime.h>

#define BATCH   1024
#define MAXLEN  200
#define KCAPS   8
#define INU     256
#define OUTU    256
#define NEGPAD  -65535.0f
#define HSTR    264   // padded LDS row stride (floats)

typedef _Float16 f16;
typedef _Float16 f16x8 __attribute__((ext_vector_type(8)));
typedef float    f32x4 __attribute__((ext_vector_type(4)));

// ---------------- prep: Bcur copy + packed-frag S and S^T (hi/lo f16) ------
__global__ void k_prep(const float* __restrict__ S, const float* __restrict__ Bm,
                       f16* __restrict__ Shi, f16* __restrict__ Slo,
                       f16* __restrict__ Thi, f16* __restrict__ Tlo,
                       float* __restrict__ Bcur) {
    int idx = blockIdx.x * 256 + threadIdx.x;    // 0 .. 65535
    if (idx < KCAPS * MAXLEN) Bcur[idx] = Bm[idx];
    int j    = idx & 7;
    int lane = (idx >> 3) & 63;
    int nf   = (idx >> 9) & 15;
    int ks   = idx >> 13;
    int k = ks * 32 + (lane >> 4) * 8 + j;
    int n = nf * 16 + (lane & 15);
    float vS = S[k * 256 + n];
    f16 hS = (f16)vS;
    Shi[idx] = hS;
    Slo[idx] = (f16)(vS - (float)hS);
    float vT = S[n * 256 + k];
    f16 hT = (f16)vT;
    Thi[idx] = hT;
    Tlo[idx] = (f16)(vT - (float)hT);
}

// phase-E: load-only part (independent of T -> hoistable above phase D)
#define ELOAD(MF, VA, VB) do {                                                       \
    const int l_  = (MF) * 16 + r15;                                                 \
    const int lc_ = (l_ < MAXLEN) ? l_ : (MAXLEN - 1);                               \
    const float* ap_ = lb + (size_t)lc_ * INU + q * 8;                               \
    _Pragma("unroll")                                                                \
    for (int ks = 0; ks < 8; ks++) {                                                 \
        VA[ks] = *reinterpret_cast<const f32x4*>(ap_ + ks * 32);                     \
        VB[ks] = *reinterpret_cast<const f32x4*>(ap_ + ks * 32 + 4);                 \
    }                                                                                \
} while (0)

// phase-E: convert + MFMA part (reads GH-as-Tl; must follow the Tl barrier)
#define ECOMP(VA, VB, ACC) do {                                                      \
    _Pragma("unroll")                                                                \
    for (int ks = 0; ks < 8; ks++) {                                                 \
        const int ob_ = ks * 32 + q * 8;                                             \
        f32x4 h0 = *reinterpret_cast<const f32x4*>(&GH[r15 * HSTR + ob_]);           \
        f32x4 h1 = *reinterpret_cast<const f32x4*>(&GH[r15 * HSTR + ob_ + 4]);       \
        f16x8 bh, bl, ah, al;                                                        \
        _Pragma("unroll")                                                            \
        for (int j = 0; j < 4; j++) { f16 t = (f16)h0[j]; bh[j] = t; bl[j] = (f16)(h0[j] - (float)t); } \
        _Pragma("unroll")                                                            \
        for (int j = 0; j < 4; j++) { f16 t = (f16)h1[j]; bh[4+j] = t; bl[4+j] = (f16)(h1[j] - (float)t); } \
        _Pragma("unroll")                                                            \
        for (int j = 0; j < 4; j++) { f16 t = (f16)VA[ks][j]; ah[j] = t; al[j] = (f16)(VA[ks][j] - (float)t); } \
        _Pragma("unroll")                                                            \
        for (int j = 0; j < 4; j++) { f16 t = (f16)VB[ks][j]; ah[4+j] = t; al[4+j] = (f16)(VB[ks][j] - (float)t); } \
        ACC = __builtin_amdgcn_mfma_f32_16x16x32_f16(ah, bh, ACC, 0, 0, 0);          \
        ACC = __builtin_amdgcn_mfma_f32_16x16x32_f16(al, bh, ACC, 0, 0, 0);          \
        ACC = __builtin_amdgcn_mfma_f32_16x16x32_f16(ah, bl, ACC, 0, 0, 0);          \
    }                                                                                \
} while (0)

// ---------------- fused per-iteration kernel --------------------------------
// A: softmax (wave per k; masked rows have W = 0 exactly via exp underflow).
// B: G = W @ low, masked, 4-row chunks/wave, PREFETCH DISTANCE 2 (r/s/t).
// C: MFMA absorbs bank sum (shfl_xor 32), squash.  D: T = H @ S^T (MFMA),
//    with phase-E frag-A loads hoisted above it.  E: delta (MFMA, b-major).
__global__ __launch_bounds__(512, 4) void k_G(const float* __restrict__ Bcur,
                                              const int*   __restrict__ seq_len,
                                              const float* __restrict__ low,
                                              const f16*   __restrict__ Shi,
                                              const f16*   __restrict__ Slo,
                                              const f16*   __restrict__ Thi,
                                              const f16*   __restrict__ Tlo,
                                              float*       __restrict__ partials,
                                              float*       __restrict__ out,
                                              int do_T) {
    __shared__ float Wl[KCAPS * MAXLEN];     // 6.4 KB
    __shared__ float GH[16 * HSTR];          // 16.9 KB: Gbanks -> Hl -> Tl
    const int b   = blockIdx.x;
    const int tid = threadIdx.x;
    const int len = seq_len[b];

    for (int i = tid; i < KCAPS * MAXLEN; i += 512) Wl[i] = Bcur[i];
    __syncthreads();

    // phase A: masked softmax, one 64-lane wave per k
    {
        const int k  = tid >> 6;
        const int ln = tid & 63;
        float m = -3.4e38f;
        for (int l = ln; l < MAXLEN; l += 64) {
            float v = (l < len) ? Wl[k * MAXLEN + l] : NEGPAD;
            m = fmaxf(m, v);
        }
        #pragma unroll
        for (int off = 32; off >= 1; off >>= 1) m = fmaxf(m, __shfl_xor(m, off));
        float ssum = 0.f;
        for (int l = ln; l < MAXLEN; l += 64) {
            float v = (l < len) ? Wl[k * MAXLEN + l] : NEGPAD;
            ssum += __expf(v - m);
        }
        #pragma unroll
        for (int off = 32; off >= 1; off >>= 1) ssum += __shfl_xor(ssum, off);
        float inv = 1.f / ssum;
        for (int l = ln; l < MAXLEN; l += 64) {
            float v = (l < len) ? Wl[k * MAXLEN + l] : NEGPAD;
            Wl[k * MAXLEN + l] = __expf(v - m) * inv;   // exactly 0 for l>=len (len>0)
        }
    }
    __syncthreads();

    const float* lb = low + (size_t)b * (MAXLEN * INU);
    const int wv = tid >> 6, lane = tid & 63;
    const int r15 = lane & 15, q = lane >> 4;

    // phase B: masked, 4-row chunks per wave (stride 8 chunks), f32x4 loads,
    // PREFETCH DISTANCE 2: r = current, s = +8, t = +16 (8 KB in flight).
    // Tail rows (l in [lim, 4*nb)) have W == 0 exactly and l <= 199: safe.
    {
        const int lim = (len == 0) ? MAXLEN : len;
        const int nb  = (lim + 3) >> 2;              // # 4-row chunks
        const float* cb = lb + lane * 4;
        f32x4 g[KCAPS];
        #pragma unroll
        for (int k = 0; k < KCAPS; k++) g[k] = (f32x4){0.f, 0.f, 0.f, 0.f};
        int c = wv;
        if (c < nb) {
            f32x4 r0 = *reinterpret_cast<const f32x4*>(cb + (size_t)(4 * c + 0) * INU);
            f32x4 r1 = *reinterpret_cast<const f32x4*>(cb + (size_t)(4 * c + 1) * INU);
            f32x4 r2 = *reinterpret_cast<const f32x4*>(cb + (size_t)(4 * c + 2) * INU);
            f32x4 r3 = *reinterpret_cast<const f32x4*>(cb + (size_t)(4 * c + 3) * INU);
            bool haveS = (c + 8 < nb);               // wave-uniform
            f32x4 s0, s1, s2, s3;
            if (haveS) {
                s0 = *reinterpret_cast<const f32x4*>(cb + (size_t)(4 * (c + 8) + 0) * INU);
                s1 = *reinterpret_cast<const f32x4*>(cb + (size_t)(4 * (c + 8) + 1) * INU);
                s2 = *reinterpret_cast<const f32x4*>(cb + (size_t)(4 * (c + 8) + 2) * INU);
                s3 = *reinterpret_cast<const f32x4*>(cb + (size_t)(4 * (c + 8) + 3) * INU);
            }
            for (;;) {
                const bool haveT = (c + 16 < nb);    // wave-uniform
                f32x4 t0, t1, t2, t3;
                if (haveT) {
                    t0 = *reinterpret_cast<const f32x4*>(cb + (size_t)(4 * (c + 16) + 0) * INU);
                    t1 = *reinterpret_cast<const f32x4*>(cb + (size_t)(4 * (c + 16) + 1) * INU);
                    t2 = *reinterpret_cast<const f32x4*>(cb + (size_t)(4 * (c + 16) + 2) * INU);
                    t3 = *reinterpret_cast<const f32x4*>(cb + (size_t)(4 * (c + 16) + 3) * INU);
                }
                const int l0 = 4 * c;
                #pragma unroll
                for (int k = 0; k < KCAPS; k++) {
                    const float w0 = Wl[k * MAXLEN + l0];       // wave-uniform broadcast
                    const float w1 = Wl[k * MAXLEN + l0 + 1];
                    const float w2 = Wl[k * MAXLEN + l0 + 2];
                    const float w3 = Wl[k * MAXLEN + l0 + 3];
                    #pragma unroll
                    for (int j = 0; j < 4; j++) {
                        g[k][j] = fmaf(w0, r0[j], g[k][j]);
                        g[k][j] = fmaf(w1, r1[j], g[k][j]);
                        g[k][j] = fmaf(w2, r2[j], g[k][j]);
                        g[k][j] = fmaf(w3, r3[j], g[k][j]);
                    }
                }
                if (!haveS) break;
                c += 8;
                r0 = s0; r1 = s1; r2 = s2; r3 = s3;
                s0 = t0; s1 = t1; s2 = t2; s3 = t3;
                haveS = haveT;
            }
        }
        // reduce 8 wave-partials: even waves -> bank0 (rows 0-7), odd -> bank1
        const int bank = wv & 1;
        const int step = wv >> 1;
        #pragma unroll
        for (int s = 0; s < 4; s++) {
            if (step == s) {
                if (s == 0) {
                    #pragma unroll
                    for (int k = 0; k < KCAPS; k++)
                        *reinterpret_cast<f32x4*>(&GH[(bank * 8 + k) * HSTR + lane * 4]) = g[k];
                } else {
                    #pragma unroll
                    for (int k = 0; k < KCAPS; k++) {
                        float* p = &GH[(bank * 8 + k) * HSTR + lane * 4];
                        f32x4 t = *reinterpret_cast<const f32x4*>(p);
                        *reinterpret_cast<f32x4*>(p) = t + g[k];
                    }
                }
            }
            __syncthreads();
        }
    }

    // phase C (MFMA): D = Gbanks(16 rows) @ S; hp[k] = D[k] + D[k+8] via
    // shfl_xor(32). Wave wv covers nf = 2wv, 2wv+1.
    f32x4 aC[2];
    aC[0] = (f32x4){0.f, 0.f, 0.f, 0.f};
    aC[1] = (f32x4){0.f, 0.f, 0.f, 0.f};
    #pragma unroll
    for (int ks = 0; ks < 8; ks++) {
        const float* gp = &GH[r15 * HSTR + ks * 32 + q * 8];
        f32x4 a0 = *reinterpret_cast<const f32x4*>(gp);
        f32x4 a1 = *reinterpret_cast<const f32x4*>(gp + 4);
        f16x8 ah, al;
        #pragma unroll
        for (int j = 0; j < 4; j++) {
            f16 t = (f16)a0[j]; ah[j] = t; al[j] = (f16)(a0[j] - (float)t);
        }
        #pragma unroll
        for (int j = 0; j < 4; j++) {
            f16 t = (f16)a1[j]; ah[4 + j] = t; al[4 + j] = (f16)(a1[j] - (float)t);
        }
        #pragma unroll
        for (int i = 0; i < 2; i++) {
            const int nf = wv * 2 + i;
            f16x8 bh = *reinterpret_cast<const f16x8*>(Shi + (ks * 16 + nf) * 512 + lane * 8);
            f16x8 bl = *reinterpret_cast<const f16x8*>(Slo + (ks * 16 + nf) * 512 + lane * 8);
            aC[i] = __builtin_amdgcn_mfma_f32_16x16x32_f16(ah, bh, aC[i], 0, 0, 0);
            aC[i] = __builtin_amdgcn_mfma_f32_16x16x32_f16(al, bh, aC[i], 0, 0, 0);
            aC[i] = __builtin_amdgcn_mfma_f32_16x16x32_f16(ah, bl, aC[i], 0, 0, 0);
        }
    }
    // bank-sum + squash: thread holds hp[k=q*4+r][o=(2wv+i)*16+r15], k<8 at q<2
    float s0, s1;
    {
        #pragma unroll
        for (int i = 0; i < 2; i++)
            #pragma unroll
            for (int r = 0; r < 4; r++) aC[i][r] += __shfl_xor(aC[i][r], 32);
        float n0 = aC[0][0]*aC[0][0] + aC[0][1]*aC[0][1] + aC[0][2]*aC[0][2] + aC[0][3]*aC[0][3];
        float n1 = aC[1][0]*aC[1][0] + aC[1][1]*aC[1][1] + aC[1][2]*aC[1][2] + aC[1][3]*aC[1][3];
        n0 += __shfl_xor(n0, 16);
        n1 += __shfl_xor(n1, 16);
        s0 = n0 / (1.f + n0) * (1.f / sqrtf(n0 + 1e-9f));
        s1 = n1 / (1.f + n1) * (1.f / sqrtf(n1 + 1e-9f));
    }
    if (!do_T) {
        if (q < 2) {
            #pragma unroll
            for (int r = 0; r < 4; r++) {
                out[((size_t)b * KCAPS + q * 4 + r) * OUTU + (wv * 2 + 0) * 16 + r15] = s0 * aC[0][r];
                out[((size_t)b * KCAPS + q * 4 + r) * OUTU + (wv * 2 + 1) * 16 + r15] = s1 * aC[1][r];
            }
        }
        return;
    }
    __syncthreads();                       // all phase-C reads of GH done
    // GH becomes Hl: rows 0-7 = H, rows 8-15 = 0 (every lane writes its cell)
    #pragma unroll
    for (int r = 0; r < 4; r++) {
        GH[(q * 4 + r) * HSTR + (wv * 2 + 0) * 16 + r15] = (q < 2) ? s0 * aC[0][r] : 0.f;
        GH[(q * 4 + r) * HSTR + (wv * 2 + 1) * 16 + r15] = (q < 2) ? s1 * aC[1][r] : 0.f;
    }
    __syncthreads();

    // hoisted phase-E frag-A loads: pure global reads of lb, independent of T;
    // latency hides under phase D's MFMAs + the two barriers below.
    f32x4 vaA[8], vbA[8];
    ELOAD(wv, vaA, vbA);

    // phase D (MFMA): T[k][e] = sum_o H[k][o]*S[e][o]
    f32x4 aD[2];
    aD[0] = (f32x4){0.f, 0.f, 0.f, 0.f};
    aD[1] = (f32x4){0.f, 0.f, 0.f, 0.f};
    #pragma unroll
    for (int ks = 0; ks < 8; ks++) {
        const float* hp = &GH[r15 * HSTR + ks * 32 + q * 8];
        f32x4 a0 = *reinterpret_cast<const f32x4*>(hp);
        f32x4 a1 = *reinterpret_cast<const f32x4*>(hp + 4);
        f16x8 ah, al;
        #pragma unroll
        for (int j = 0; j < 4; j++) {
            f16 t = (f16)a0[j]; ah[j] = t; al[j] = (f16)(a0[j] - (float)t);
        }
        #pragma unroll
        for (int j = 0; j < 4; j++) {
            f16 t = (f16)a1[j]; ah[4 + j] = t; al[4 + j] = (f16)(a1[j] - (float)t);
        }
        #pragma unroll
        for (int i = 0; i < 2; i++) {
            const int nf = wv * 2 + i;
            f16x8 bh = *reinterpret_cast<const f16x8*>(Thi + (ks * 16 + nf) * 512 + lane * 8);
            f16x8 bl = *reinterpret_cast<const f16x8*>(Tlo + (ks * 16 + nf) * 512 + lane * 8);
            aD[i] = __builtin_amdgcn_mfma_f32_16x16x32_f16(ah, bh, aD[i], 0, 0, 0);
            aD[i] = __builtin_amdgcn_mfma_f32_16x16x32_f16(al, bh, aD[i], 0, 0, 0);
            aD[i] = __builtin_amdgcn_mfma_f32_16x16x32_f16(ah, bl, aD[i], 0, 0, 0);
        }
    }
    __syncthreads();                       // all phase-D reads of GH done
    // GH becomes Tl: rows 0-7 = T, rows 8-15 = 0
    #pragma unroll
    for (int r = 0; r < 4; r++) {
        GH[(q * 4 + r) * HSTR + (wv * 2 + 0) * 16 + r15] = (q < 2) ? aD[0][r] : 0.f;
        GH[(q * 4 + r) * HSTR + (wv * 2 + 1) * 16 + r15] = (q < 2) ? aD[1][r] : 0.f;
    }
    __syncthreads();

    // phase E (MFMA): delta_T[l][k] = sum_e low[l,e]*T[k,e]; b-major partials
    f32x4 accA = (f32x4){0.f, 0.f, 0.f, 0.f};
    f32x4 accB = (f32x4){0.f, 0.f, 0.f, 0.f};
    ECOMP(vaA, vbA, accA);
    if (wv < 5) {
        f32x4 vaB[8], vbB[8];
        ELOAD(wv + 8, vaB, vbB);
        ECOMP(vaB, vbB, accB);
    }

    if (r15 < KCAPS) {
        const int kcol = r15;
        float* pb = partials + (size_t)b * (KCAPS * MAXLEN);
        {   // frag A rows: l = wv*16 + q*4 + r  (max 127 < 200, no guard)
            const int lbase = wv * 16 + q * 4;
            #pragma unroll
            for (int r = 0; r < 4; r++)
                pb[(lbase + r) * KCAPS + kcol] = accA[r];
        }
        if (wv < 5) {   // frag B rows: l = (wv+8)*16 + q*4 + r (may exceed 199)
            const int lbase = (wv + 8) * 16 + q * 4;
            #pragma unroll
            for (int r = 0; r < 4; r++) {
                const int l = lbase + r;
                if (l < MAXLEN)
                    pb[l * KCAPS + kcol] = accB[r];
            }
        }
    }
}

// ---------------- B update: Bcur[k*200+l] += sum_b partials[b][l*8+k] ------
__global__ __launch_bounds__(256) void k_update(const float* __restrict__ partials,
                                                float* __restrict__ Bcur) {
    __shared__ float red[256];
    const int j   = blockIdx.x;            // 0..1599 ; l = j>>3, k = j&7
    const int tid = threadIdx.x;
    float s = 0.f;
    #pragma unroll
    for (int jj = 0; jj < BATCH / 256; jj++)
        s += partials[(size_t)(tid + jj * 256) * (KCAPS * MAXLEN) + j];
    red[tid] = s;
    __syncthreads();
    for (int st = 128; st > 0; st >>= 1) {
        if (tid < st) red[tid] += red[tid + st];
        __syncthreads();
    }
    if (tid == 0) Bcur[(j & 7) * MAXLEN + (j >> 3)] += red[0];
}

extern "C" void kernel_launch(void* const* d_in, const int* in_sizes, int n_in,
                              void* d_out, int out_size, void* d_ws, size_t ws_size,
                              hipStream_t stream) {
    const float* low = (const float*)d_in[0];
    const float* S   = (const float*)d_in[1];
    const float* Bm  = (const float*)d_in[2];
    const int*   seq = (const int*)d_in[3];
    float* out = (float*)d_out;

    char* ws = (char*)d_ws;
    float* Bcur     = (float*)ws;                     // 6,400 B
    float* partials = (float*)(ws + 6400);            // 6,553,600 B
    f16*   Shi      = (f16*)(ws + 6560000);           // 131,072 B
    f16*   Slo      = (f16*)(ws + 6691072);           // 131,072 B
    f16*   Thi      = (f16*)(ws + 6822144);           // 131,072 B
    f16*   Tlo      = (f16*)(ws + 6953216);           // 131,072 B

    k_prep<<<256, 256, 0, stream>>>(S, Bm, Shi, Slo, Thi, Tlo, Bcur);
    for (int it = 0; it < 3; it++) {
        int last = (it == 2);
        k_G<<<BATCH, 512, 0, stream>>>(Bcur, seq, low, Shi, Slo, Thi, Tlo,
                                       partials, out, last ? 0 : 1);
        if (!last) k_update<<<KCAPS * MAXLEN, 256, 0, stream>>>(partials, Bcur);
    }
}

// Round 19
// 183.985 us; speedup vs baseline: 1.3202x; 1.0624x over previous
//
#include <hip/hip_runtime.h>

#define BATCH   1024
#define MAXLEN  200
#define KCAPS   8
#define INU     256
#define OUTU    256
#define NEGPAD  -65535.0f
#define HSTR    264   // padded LDS row stride (floats)

typedef _Float16 f16;
typedef _Float16 f16x8 __attribute__((ext_vector_type(8)));
typedef float    f32x4 __attribute__((ext_vector_type(4)));

// ---------------- prep: Bcur copy + packed-frag S and S^T (hi/lo f16) ------
__global__ void k_prep(const float* __restrict__ S, const float* __restrict__ Bm,
                       f16* __restrict__ Shi, f16* __restrict__ Slo,
                       f16* __restrict__ Thi, f16* __restrict__ Tlo,
                       float* __restrict__ Bcur) {
    int idx = blockIdx.x * 256 + threadIdx.x;    // 0 .. 65535
    if (idx < KCAPS * MAXLEN) Bcur[idx] = Bm[idx];
    int j    = idx & 7;
    int lane = (idx >> 3) & 63;
    int nf   = (idx >> 9) & 15;
    int ks   = idx >> 13;
    int k = ks * 32 + (lane >> 4) * 8 + j;
    int n = nf * 16 + (lane & 15);
    float vS = S[k * 256 + n];
    f16 hS = (f16)vS;
    Shi[idx] = hS;
    Slo[idx] = (f16)(vS - (float)hS);
    float vT = S[n * 256 + k];
    f16 hT = (f16)vT;
    Thi[idx] = hT;
    Tlo[idx] = (f16)(vT - (float)hT);
}

// phase-E: load-only part (independent of T -> hoistable above phase D)
#define ELOAD(MF, VA, VB) do {                                                       \
    const int l_  = (MF) * 16 + r15;                                                 \
    const int lc_ = (l_ < MAXLEN) ? l_ : (MAXLEN - 1);                               \
    const float* ap_ = lb + (size_t)lc_ * INU + q * 8;                               \
    _Pragma("unroll")                                                                \
    for (int ks = 0; ks < 8; ks++) {                                                 \
        VA[ks] = *reinterpret_cast<const f32x4*>(ap_ + ks * 32);                     \
        VB[ks] = *reinterpret_cast<const f32x4*>(ap_ + ks * 32 + 4);                 \
    }                                                                                \
} while (0)

// phase-E: convert + MFMA part (reads GH-as-Tl; must follow the Tl barrier)
#define ECOMP(VA, VB, ACC) do {                                                      \
    _Pragma("unroll")                                                                \
    for (int ks = 0; ks < 8; ks++) {                                                 \
        const int ob_ = ks * 32 + q * 8;                                             \
        f32x4 h0 = *reinterpret_cast<const f32x4*>(&GH[r15 * HSTR + ob_]);           \
        f32x4 h1 = *reinterpret_cast<const f32x4*>(&GH[r15 * HSTR + ob_ + 4]);       \
        f16x8 bh, bl, ah, al;                                                        \
        _Pragma("unroll")                                                            \
        for (int j = 0; j < 4; j++) { f16 t = (f16)h0[j]; bh[j] = t; bl[j] = (f16)(h0[j] - (float)t); } \
        _Pragma("unroll")                                                            \
        for (int j = 0; j < 4; j++) { f16 t = (f16)h1[j]; bh[4+j] = t; bl[4+j] = (f16)(h1[j] - (float)t); } \
        _Pragma("unroll")                                                            \
        for (int j = 0; j < 4; j++) { f16 t = (f16)VA[ks][j]; ah[j] = t; al[j] = (f16)(VA[ks][j] - (float)t); } \
        _Pragma("unroll")                                                            \
        for (int j = 0; j < 4; j++) { f16 t = (f16)VB[ks][j]; ah[4+j] = t; al[4+j] = (f16)(VB[ks][j] - (float)t); } \
        ACC = __builtin_amdgcn_mfma_f32_16x16x32_f16(ah, bh, ACC, 0, 0, 0);          \
        ACC = __builtin_amdgcn_mfma_f32_16x16x32_f16(al, bh, ACC, 0, 0, 0);          \
        ACC = __builtin_amdgcn_mfma_f32_16x16x32_f16(ah, bl, ACC, 0, 0, 0);          \
    }                                                                                \
} while (0)

// ---------------- fused per-iteration kernel (identical to R18) -------------
__global__ __launch_bounds__(512, 4) void k_G(const float* __restrict__ Bcur,
                                              const int*   __restrict__ seq_len,
                                              const float* __restrict__ low,
                                              const f16*   __restrict__ Shi,
                                              const f16*   __restrict__ Slo,
                                              const f16*   __restrict__ Thi,
                                              const f16*   __restrict__ Tlo,
                                              float*       __restrict__ partials,
                                              float*       __restrict__ out,
                                              int do_T) {
    __shared__ float Wl[KCAPS * MAXLEN];     // 6.4 KB
    __shared__ float GH[16 * HSTR];          // 16.9 KB: Gbanks -> Hl -> Tl
    const int b   = blockIdx.x;
    const int tid = threadIdx.x;
    const int len = seq_len[b];

    for (int i = tid; i < KCAPS * MAXLEN; i += 512) Wl[i] = Bcur[i];
    __syncthreads();

    // phase A: masked softmax, one 64-lane wave per k
    {
        const int k  = tid >> 6;
        const int ln = tid & 63;
        float m = -3.4e38f;
        for (int l = ln; l < MAXLEN; l += 64) {
            float v = (l < len) ? Wl[k * MAXLEN + l] : NEGPAD;
            m = fmaxf(m, v);
        }
        #pragma unroll
        for (int off = 32; off >= 1; off >>= 1) m = fmaxf(m, __shfl_xor(m, off));
        float ssum = 0.f;
        for (int l = ln; l < MAXLEN; l += 64) {
            float v = (l < len) ? Wl[k * MAXLEN + l] : NEGPAD;
            ssum += __expf(v - m);
        }
        #pragma unroll
        for (int off = 32; off >= 1; off >>= 1) ssum += __shfl_xor(ssum, off);
        float inv = 1.f / ssum;
        for (int l = ln; l < MAXLEN; l += 64) {
            float v = (l < len) ? Wl[k * MAXLEN + l] : NEGPAD;
            Wl[k * MAXLEN + l] = __expf(v - m) * inv;   // exactly 0 for l>=len (len>0)
        }
    }
    __syncthreads();

    const float* lb = low + (size_t)b * (MAXLEN * INU);
    const int wv = tid >> 6, lane = tid & 63;
    const int r15 = lane & 15, q = lane >> 4;

    // phase B: masked, 4-row chunks per wave (stride 8 chunks), f32x4 loads,
    // prefetch distance 2 (r/s/t).
    {
        const int lim = (len == 0) ? MAXLEN : len;
        const int nb  = (lim + 3) >> 2;
        const float* cb = lb + lane * 4;
        f32x4 g[KCAPS];
        #pragma unroll
        for (int k = 0; k < KCAPS; k++) g[k] = (f32x4){0.f, 0.f, 0.f, 0.f};
        int c = wv;
        if (c < nb) {
            f32x4 r0 = *reinterpret_cast<const f32x4*>(cb + (size_t)(4 * c + 0) * INU);
            f32x4 r1 = *reinterpret_cast<const f32x4*>(cb + (size_t)(4 * c + 1) * INU);
            f32x4 r2 = *reinterpret_cast<const f32x4*>(cb + (size_t)(4 * c + 2) * INU);
            f32x4 r3 = *reinterpret_cast<const f32x4*>(cb + (size_t)(4 * c + 3) * INU);
            bool haveS = (c + 8 < nb);
            f32x4 s0, s1, s2, s3;
            if (haveS) {
                s0 = *reinterpret_cast<const f32x4*>(cb + (size_t)(4 * (c + 8) + 0) * INU);
                s1 = *reinterpret_cast<const f32x4*>(cb + (size_t)(4 * (c + 8) + 1) * INU);
                s2 = *reinterpret_cast<const f32x4*>(cb + (size_t)(4 * (c + 8) + 2) * INU);
                s3 = *reinterpret_cast<const f32x4*>(cb + (size_t)(4 * (c + 8) + 3) * INU);
            }
            for (;;) {
                const bool haveT = (c + 16 < nb);
                f32x4 t0, t1, t2, t3;
                if (haveT) {
                    t0 = *reinterpret_cast<const f32x4*>(cb + (size_t)(4 * (c + 16) + 0) * INU);
                    t1 = *reinterpret_cast<const f32x4*>(cb + (size_t)(4 * (c + 16) + 1) * INU);
                    t2 = *reinterpret_cast<const f32x4*>(cb + (size_t)(4 * (c + 16) + 2) * INU);
                    t3 = *reinterpret_cast<const f32x4*>(cb + (size_t)(4 * (c + 16) + 3) * INU);
                }
                const int l0 = 4 * c;
                #pragma unroll
                for (int k = 0; k < KCAPS; k++) {
                    const float w0 = Wl[k * MAXLEN + l0];
                    const float w1 = Wl[k * MAXLEN + l0 + 1];
                    const float w2 = Wl[k * MAXLEN + l0 + 2];
                    const float w3 = Wl[k * MAXLEN + l0 + 3];
                    #pragma unroll
                    for (int j = 0; j < 4; j++) {
                        g[k][j] = fmaf(w0, r0[j], g[k][j]);
                        g[k][j] = fmaf(w1, r1[j], g[k][j]);
                        g[k][j] = fmaf(w2, r2[j], g[k][j]);
                        g[k][j] = fmaf(w3, r3[j], g[k][j]);
                    }
                }
                if (!haveS) break;
                c += 8;
                r0 = s0; r1 = s1; r2 = s2; r3 = s3;
                s0 = t0; s1 = t1; s2 = t2; s3 = t3;
                haveS = haveT;
            }
        }
        const int bank = wv & 1;
        const int step = wv >> 1;
        #pragma unroll
        for (int s = 0; s < 4; s++) {
            if (step == s) {
                if (s == 0) {
                    #pragma unroll
                    for (int k = 0; k < KCAPS; k++)
                        *reinterpret_cast<f32x4*>(&GH[(bank * 8 + k) * HSTR + lane * 4]) = g[k];
                } else {
                    #pragma unroll
                    for (int k = 0; k < KCAPS; k++) {
                        float* p = &GH[(bank * 8 + k) * HSTR + lane * 4];
                        f32x4 t = *reinterpret_cast<const f32x4*>(p);
                        *reinterpret_cast<f32x4*>(p) = t + g[k];
                    }
                }
            }
            __syncthreads();
        }
    }

    // phase C (MFMA)
    f32x4 aC[2];
    aC[0] = (f32x4){0.f, 0.f, 0.f, 0.f};
    aC[1] = (f32x4){0.f, 0.f, 0.f, 0.f};
    #pragma unroll
    for (int ks = 0; ks < 8; ks++) {
        const float* gp = &GH[r15 * HSTR + ks * 32 + q * 8];
        f32x4 a0 = *reinterpret_cast<const f32x4*>(gp);
        f32x4 a1 = *reinterpret_cast<const f32x4*>(gp + 4);
        f16x8 ah, al;
        #pragma unroll
        for (int j = 0; j < 4; j++) {
            f16 t = (f16)a0[j]; ah[j] = t; al[j] = (f16)(a0[j] - (float)t);
        }
        #pragma unroll
        for (int j = 0; j < 4; j++) {
            f16 t = (f16)a1[j]; ah[4 + j] = t; al[4 + j] = (f16)(a1[j] - (float)t);
        }
        #pragma unroll
        for (int i = 0; i < 2; i++) {
            const int nf = wv * 2 + i;
            f16x8 bh = *reinterpret_cast<const f16x8*>(Shi + (ks * 16 + nf) * 512 + lane * 8);
            f16x8 bl = *reinterpret_cast<const f16x8*>(Slo + (ks * 16 + nf) * 512 + lane * 8);
            aC[i] = __builtin_amdgcn_mfma_f32_16x16x32_f16(ah, bh, aC[i], 0, 0, 0);
            aC[i] = __builtin_amdgcn_mfma_f32_16x16x32_f16(al, bh, aC[i], 0, 0, 0);
            aC[i] = __builtin_amdgcn_mfma_f32_16x16x32_f16(ah, bl, aC[i], 0, 0, 0);
        }
    }
    float s0, s1;
    {
        #pragma unroll
        for (int i = 0; i < 2; i++)
            #pragma unroll
            for (int r = 0; r < 4; r++) aC[i][r] += __shfl_xor(aC[i][r], 32);
        float n0 = aC[0][0]*aC[0][0] + aC[0][1]*aC[0][1] + aC[0][2]*aC[0][2] + aC[0][3]*aC[0][3];
        float n1 = aC[1][0]*aC[1][0] + aC[1][1]*aC[1][1] + aC[1][2]*aC[1][2] + aC[1][3]*aC[1][3];
        n0 += __shfl_xor(n0, 16);
        n1 += __shfl_xor(n1, 16);
        s0 = n0 / (1.f + n0) * (1.f / sqrtf(n0 + 1e-9f));
        s1 = n1 / (1.f + n1) * (1.f / sqrtf(n1 + 1e-9f));
    }
    if (!do_T) {
        if (q < 2) {
            #pragma unroll
            for (int r = 0; r < 4; r++) {
                out[((size_t)b * KCAPS + q * 4 + r) * OUTU + (wv * 2 + 0) * 16 + r15] = s0 * aC[0][r];
                out[((size_t)b * KCAPS + q * 4 + r) * OUTU + (wv * 2 + 1) * 16 + r15] = s1 * aC[1][r];
            }
        }
        return;
    }
    __syncthreads();
    #pragma unroll
    for (int r = 0; r < 4; r++) {
        GH[(q * 4 + r) * HSTR + (wv * 2 + 0) * 16 + r15] = (q < 2) ? s0 * aC[0][r] : 0.f;
        GH[(q * 4 + r) * HSTR + (wv * 2 + 1) * 16 + r15] = (q < 2) ? s1 * aC[1][r] : 0.f;
    }
    __syncthreads();

    // hoisted phase-E frag-A loads
    f32x4 vaA[8], vbA[8];
    ELOAD(wv, vaA, vbA);

    // phase D (MFMA)
    f32x4 aD[2];
    aD[0] = (f32x4){0.f, 0.f, 0.f, 0.f};
    aD[1] = (f32x4){0.f, 0.f, 0.f, 0.f};
    #pragma unroll
    for (int ks = 0; ks < 8; ks++) {
        const float* hp = &GH[r15 * HSTR + ks * 32 + q * 8];
        f32x4 a0 = *reinterpret_cast<const f32x4*>(hp);
        f32x4 a1 = *reinterpret_cast<const f32x4*>(hp + 4);
        f16x8 ah, al;
        #pragma unroll
        for (int j = 0; j < 4; j++) {
            f16 t = (f16)a0[j]; ah[j] = t; al[j] = (f16)(a0[j] - (float)t);
        }
        #pragma unroll
        for (int j = 0; j < 4; j++) {
            f16 t = (f16)a1[j]; ah[4 + j] = t; al[4 + j] = (f16)(a1[j] - (float)t);
        }
        #pragma unroll
        for (int i = 0; i < 2; i++) {
            const int nf = wv * 2 + i;
            f16x8 bh = *reinterpret_cast<const f16x8*>(Thi + (ks * 16 + nf) * 512 + lane * 8);
            f16x8 bl = *reinterpret_cast<const f16x8*>(Tlo + (ks * 16 + nf) * 512 + lane * 8);
            aD[i] = __builtin_amdgcn_mfma_f32_16x16x32_f16(ah, bh, aD[i], 0, 0, 0);
            aD[i] = __builtin_amdgcn_mfma_f32_16x16x32_f16(al, bh, aD[i], 0, 0, 0);
            aD[i] = __builtin_amdgcn_mfma_f32_16x16x32_f16(ah, bl, aD[i], 0, 0, 0);
        }
    }
    __syncthreads();
    #pragma unroll
    for (int r = 0; r < 4; r++) {
        GH[(q * 4 + r) * HSTR + (wv * 2 + 0) * 16 + r15] = (q < 2) ? aD[0][r] : 0.f;
        GH[(q * 4 + r) * HSTR + (wv * 2 + 1) * 16 + r15] = (q < 2) ? aD[1][r] : 0.f;
    }
    __syncthreads();

    // phase E (MFMA): b-major partials
    f32x4 accA = (f32x4){0.f, 0.f, 0.f, 0.f};
    f32x4 accB = (f32x4){0.f, 0.f, 0.f, 0.f};
    ECOMP(vaA, vbA, accA);
    if (wv < 5) {
        f32x4 vaB[8], vbB[8];
        ELOAD(wv + 8, vaB, vbB);
        ECOMP(vaB, vbB, accB);
    }

    if (r15 < KCAPS) {
        const int kcol = r15;
        float* pb = partials + (size_t)b * (KCAPS * MAXLEN);
        {
            const int lbase = wv * 16 + q * 4;
            #pragma unroll
            for (int r = 0; r < 4; r++)
                pb[(lbase + r) * KCAPS + kcol] = accA[r];
        }
        if (wv < 5) {
            const int lbase = (wv + 8) * 16 + q * 4;
            #pragma unroll
            for (int r = 0; r < 4; r++) {
                const int l = lbase + r;
                if (l < MAXLEN)
                    pb[l * KCAPS + kcol] = accB[r];
            }
        }
    }
}

// ---------------- B update (coalesced): block handles 16 consecutive j ------
// partials[b][j], j = l*8+k.  Thread t: jj = t&15, bgrp = t>>4; sums over
// b = bgrp + 16*i (i=0..63).  16 consecutive lanes read one contiguous 64B
// line -> full line utilization.  LDS tree reduces the 16 b-groups per jj.
__global__ __launch_bounds__(256) void k_update(const float* __restrict__ partials,
                                                float* __restrict__ Bcur) {
    __shared__ float red[256];
    const int j0   = blockIdx.x * 16;      // 100 blocks x 16 j
    const int tid  = threadIdx.x;
    const int jj   = tid & 15;
    const int bgrp = tid >> 4;             // 0..15
    float s = 0.f;
    #pragma unroll 8
    for (int i = 0; i < 64; i++) {
        const int b = bgrp + i * 16;
        s += partials[(size_t)b * (KCAPS * MAXLEN) + j0 + jj];
    }
    red[tid] = s;
    __syncthreads();
    // reduce over bgrp (stride-16 lanes share jj)
    for (int st = 8; st > 0; st >>= 1) {
        if (bgrp < st) red[tid] += red[tid + st * 16];
        __syncthreads();
    }
    if (tid < 16) {
        const int j = j0 + tid;
        Bcur[(j & 7) * MAXLEN + (j >> 3)] += red[tid];
    }
}

extern "C" void kernel_launch(void* const* d_in, const int* in_sizes, int n_in,
                              void* d_out, int out_size, void* d_ws, size_t ws_size,
                              hipStream_t stream) {
    const float* low = (const float*)d_in[0];
    const float* S   = (const float*)d_in[1];
    const float* Bm  = (const float*)d_in[2];
    const int*   seq = (const int*)d_in[3];
    float* out = (float*)d_out;

    char* ws = (char*)d_ws;
    float* Bcur     = (float*)ws;                     // 6,400 B
    float* partials = (float*)(ws + 6400);            // 6,553,600 B
    f16*   Shi      = (f16*)(ws + 6560000);           // 131,072 B
    f16*   Slo      = (f16*)(ws + 6691072);           // 131,072 B
    f16*   Thi      = (f16*)(ws + 6822144);           // 131,072 B
    f16*   Tlo      = (f16*)(ws + 6953216);           // 131,072 B

    k_prep<<<256, 256, 0, stream>>>(S, Bm, Shi, Slo, Thi, Tlo, Bcur);
    for (int it = 0; it < 3; it++) {
        int last = (it == 2);
        k_G<<<BATCH, 512, 0, stream>>>(Bcur, seq, low, Shi, Slo, Thi, Tlo,
                                       partials, out, last ? 0 : 1);
        if (!last) k_update<<<100, 256, 0, stream>>>(partials, Bcur);
    }
}